// Round 9
// baseline (412.337 us; speedup 1.0000x reference)
//
#include <hip/hip_runtime.h>
#include <hip/hip_fp16.h>

// SSIM, B=16, C=1, H=W=1024, 11x11 separable Gaussian.
// v8: disciplined K=2 columns/lane. v6 proved the K=2 dataflow correct
// (absmax 0.0) and the VALU reduction real; it spilled (VGPR capped 128 by
// launch_bounds(256,2), 84 array temps -> 95MB scratch). Fixes:
//   (1) __launch_bounds__(256,1): VGPR cap lifted; allocator free (~160-190).
//   (2) sequential exchange phases through hblur12 helper; peak temp
//       liveness ~18 regs, no 12-wide tap arrays.
//   (3) exchange PRODUCTS (packed half2) instead of d: 3x6 + 2x6 = 30
//       bpermutes/step for 2 cols (15/col vs v4's 20/col); both-image tap
//       arrays never coexist.
// v7 lesson kept: g[] stays in VGPRs (readfirstlane starved ILP, -13%).
// Wave strip = 128 cols (lane i owns base+2i, base+2i+1), 108 useful +
// 10+10 halo; streams 84 rows of a 64-row band. Windows: img fp32 4x11,
// mu half2 2x11, products half2 3x11. All arithmetic fp32; fp16 only as
// packed storage/exchange. Finalize merged (v6/v7-validated done-counter).

#define IMG_H 1024
#define IMG_W 1024
#define USEC   108                     // useful cols per wave
#define NSTRIP 10                      // 10*108 = 1080 >= 1024
#define BAND   64                      // output rows per wave
#define NBAND  16
#define NBATCH 16
#define NWAVES (NSTRIP * NBAND * NBATCH)   // 2560
#define NBLK   (NWAVES / 4)                // 640 blocks of 4 waves

__device__ __forceinline__ unsigned fkey(float f) {
  unsigned b = __float_as_uint(f);
  return (b & 0x80000000u) ? ~b : (b | 0x80000000u);
}
__device__ __forceinline__ float funkey(unsigned k) {
  return (k & 0x80000000u) ? __uint_as_float(k & 0x7FFFFFFFu)
                           : __uint_as_float(~k);
}
__device__ __forceinline__ unsigned xlane_u(unsigned v, int addr) {
  // full-wave (64-lane) register crossbar; addr in bytes, lane = addr[7:2]
  return (unsigned)__builtin_amdgcn_ds_bpermute(addr, (int)v);
}
__device__ __forceinline__ float lo2f(unsigned u) {
  __half2 h = *(__half2*)&u; return __low2float(h);
}
__device__ __forceinline__ float hi2f(unsigned u) {
  __half2 h = *(__half2*)&u; return __high2float(h);
}
__device__ __forceinline__ unsigned packh2(float a, float b) {
  __half2 h = __floats2half2_rn(a, b); return *(unsigned*)&h;
}

// 11-tap horizontal blur for BOTH owned columns from one packed exchange.
// Lane i owns rel cols 2i (center ca) and 2i+1 (center cb); l1..l3/r1..r3 are
// the packed words from lanes i-1..i-3 / i+1..i+3. Taps (rel to 2i):
//   t0=-5 t1=-4 t2=-3 t3=-2 t4=-1 [ca=0 cb=+1] t7=+2 t8=+3 t9=+4 t10=+5 t11=+6
// Gaussian symmetric: g[5-k] == g[5+k] bitwise.
__device__ __forceinline__ void hblur12(const float* __restrict__ g,
                                        unsigned l3, unsigned l2, unsigned l1,
                                        float ca, float cb,
                                        unsigned r1, unsigned r2, unsigned r3,
                                        float& oa, float& ob) {
  const float t0 = hi2f(l3), t1 = lo2f(l2), t2 = hi2f(l2);
  const float t3 = lo2f(l1), t4 = hi2f(l1);
  const float t7 = lo2f(r1), t8 = hi2f(r1);
  const float t9 = lo2f(r2), t10 = hi2f(r2), t11 = lo2f(r3);
  float a = g[5] * ca;
  a = fmaf(g[6], t4 + cb, a);
  a = fmaf(g[7], t3 + t7, a);
  a = fmaf(g[8], t2 + t8, a);
  a = fmaf(g[9], t1 + t9, a);
  a = fmaf(g[10], t0 + t10, a);
  float b = g[5] * cb;
  b = fmaf(g[6], ca + t7, b);
  b = fmaf(g[7], t4 + t8, b);
  b = fmaf(g[8], t3 + t9, b);
  b = fmaf(g[9], t2 + t10, b);
  b = fmaf(g[10], t1 + t11, b);
  oa = a; ob = b;
}

__global__ void ssim_init(unsigned* __restrict__ ws) {
  ws[0] = 0u;           // sum S0*B0
  ws[1] = 0u;           // sum S0*B'   (C1 coefficient)
  ws[2] = 0u;           // sum B0*S'   (C2 coefficient)
  ws[3] = 0xFFFFFFFFu;  // min key
  ws[4] = 0u;           // max key
  ws[5] = 0u;           // done-counter
}

__global__ __launch_bounds__(256, 1)
void ssim_main(const float* __restrict__ img1, const float* __restrict__ img2,
               const float* __restrict__ kern, unsigned* __restrict__ ws,
               float* __restrict__ out) {
  __shared__ float redbuf[4][8];

  const int tid = threadIdx.x;
  const int lane = tid & 63;
  const int wv = tid >> 6;
  const int wid = blockIdx.x * 4 + wv;

  const int strip = wid % NSTRIP;
  const int rem = wid / NSTRIP;
  const int band = rem % NBAND;
  const int batch = rem / NBAND;

  const size_t boff = (size_t)batch * (IMG_H * IMG_W);
  const float* i1 = img1 + boff;
  const float* i2 = img2 + boff;

  // separable weights: g[j] = k2d[5][j] / sqrt(k2d[5][5]) (VGPRs: v7 showed
  // SGPR-pinning starves bpermute ILP)
  float g[11];
  #pragma unroll
  for (int j = 0; j < 11; ++j) g[j] = kern[55 + j] * rsqrtf(kern[60]);

  const int base = strip * USEC - 10;          // even -> float2-aligned
  const int c0 = base + 2 * lane;              // this lane's two columns
  const int c1v = c0 + 1;
  const bool coka = ((unsigned)c0 < IMG_W);
  const bool cokb = ((unsigned)c1v < IMG_W);
  const int cia = min(max(c0, 0), IMG_W - 1);
  const int cib = min(max(c1v, 0), IMG_W - 1);
  const bool interior = (base >= 0) && (base + 128 <= IMG_W);  // wave-uniform
  const bool omaa = (lane >= 5) && (lane <= 58) && coka;       // output masks
  const bool omab = (lane >= 5) && (lane <= 58) && cokb;
  const int r0 = band * BAND;
  const int a4 = lane * 4;

  // rolling windows (statically indexed -> registers)
  float w1a[11] = {}, w1b[11] = {}, w2a[11] = {}, w2b[11] = {};
  unsigned m1w[11] = {}, m2w[11] = {};                   // half2 (mu_a, mu_b)
  unsigned p11w[11] = {}, p22w[11] = {}, p12w[11] = {};  // half2 (hp_a, hp_b)

  float acc0 = 0.f, aC1 = 0.f, aC2 = 0.f;
  float vmin = 1e30f, vmax = -1e30f;

  auto LOADROW = [&](int rin, float2& o1, float2& o2) {
    if ((unsigned)rin < IMG_H) {
      const float* r1p = i1 + (size_t)rin * IMG_W;
      const float* r2p = i2 + (size_t)rin * IMG_W;
      if (interior) {
        o1 = *(const float2*)(r1p + c0);         // 8B coalesced
        o2 = *(const float2*)(r2p + c0);
      } else {                                   // edge strips: clamped scalar
        o1.x = r1p[cia]; o1.y = r1p[cib];
        o2.x = r2p[cia]; o2.y = r2p[cib];
      }
    } else { o1.x = 0.f; o1.y = 0.f; o2.x = 0.f; o2.y = 0.f; }
  };

  auto COMB = [&](float s11, float s22, float s12v, float M1, float M2,
                  bool ok) {
    float s1 = s11 + 1.f;                  // sigma1_sq
    float s2 = s22 + 1.f;                  // sigma2_sq
    float sv = s12v + 1.f;                 // sigma12
    float a = 2.f * sv;
    float b = s1 + s2;                     // >= 2 on valid lanes
    float rb = __builtin_amdgcn_rcpf(b);
    float S0 = a * rb;
    float Sp = (b - a) * rb * rb;          // dS/dC2
    float m12 = fmaf(M1, M2, 1.f);
    float nb = 2.f * m12;
    float N1 = nb * nb;
    float ms = fmaf(M1, M1, fmaf(M2, M2, 2.f));
    float Dv = ms * ms;                    // >= 4 on valid lanes
    float rD = __builtin_amdgcn_rcpf(Dv);
    float B0 = N1 * rD;
    float Bp = (Dv - N1) * rD * rD;        // dB/dC1
    acc0 += ok ? (S0 * B0) : 0.f;          // select blocks NaN from halo lanes
    aC1 += ok ? (S0 * Bp) : 0.f;
    aC2 += ok ? (B0 * Sp) : 0.f;
  };

  // prefetch row for t = 0 (img row r0-10)
  float2 nv1, nv2;
  LOADROW(r0 - 10, nv1, nv2);

  #pragma unroll 1
  for (int m = 0; m < 8; ++m) {
    #pragma unroll
    for (int c = 0; c < 11; ++c) {
      const int t = m * 11 + c;                // step; img row rt = r0-10+t

      // commit prefetched row t (column-masked -> zero padding)
      float v1a = coka ? nv1.x : 0.f;
      float v1b = cokb ? nv1.y : 0.f;
      float v2a = coka ? nv2.x : 0.f;
      float v2b = cokb ? nv2.y : 0.f;
      w1a[c] = v1a; w1b[c] = v1b; w2a[c] = v2a; w2b[c] = v2b;
      vmin = fminf(vmin, fminf(fminf(v1a, v1b), fminf(v2a, v2b)));
      vmax = fmaxf(vmax, fmaxf(fmaxf(v1a, v1b), fmaxf(v2a, v2b)));

      // prefetch row t+1 (latency hidden under this step's compute)
      if (t < 83) { LOADROW(r0 - 9 + t, nv1, nv2); }
      else { nv1.x = 0.f; nv1.y = 0.f; nv2.x = 0.f; nv2.y = 0.f; }

      // vertical blur over img rows rt-10..rt -> Vimg at row rt-5 (both cols)
      float V1a = 0.f, V1b = 0.f, V2a = 0.f, V2b = 0.f;
      #pragma unroll
      for (int j = 0; j < 11; ++j) {
        const int ix = (c + 1 + j) % 11;
        const float gj = g[j];
        V1a = fmaf(gj, w1a[ix], V1a); V1b = fmaf(gj, w1b[ix], V1b);
        V2a = fmaf(gj, w2a[ix], V2a); V2b = fmaf(gj, w2b[ix], V2b);
      }

      // mu, image 1 (sequential phase: 6 bpermutes + hblur12)
      float mu1a, mu1b, mu2a, mu2b;
      {
        const unsigned W = packh2(V1a, V1b);
        const unsigned l1 = xlane_u(W, a4 - 4), l2 = xlane_u(W, a4 - 8);
        const unsigned l3 = xlane_u(W, a4 - 12), r1 = xlane_u(W, a4 + 4);
        const unsigned r2 = xlane_u(W, a4 + 8), r3 = xlane_u(W, a4 + 12);
        hblur12(g, l3, l2, l1, V1a, V1b, r1, r2, r3, mu1a, mu1b);
      }
      // mu, image 2
      {
        const unsigned W = packh2(V2a, V2b);
        const unsigned l1 = xlane_u(W, a4 - 4), l2 = xlane_u(W, a4 - 8);
        const unsigned l3 = xlane_u(W, a4 - 12), r1 = xlane_u(W, a4 + 4);
        const unsigned r2 = xlane_u(W, a4 + 8), r3 = xlane_u(W, a4 + 12);
        hblur12(g, l3, l2, l1, V2a, V2b, r1, r2, r3, mu2a, mu2b);
      }
      m1w[c] = packh2(mu1a, mu1b);
      m2w[c] = packh2(mu2a, mu2b);

      // d at row rt-5 (0 outside the image, matching zero-padded second conv)
      const bool drok = ((unsigned)(r0 - 15 + t) < IMG_H);
      const int i6 = (c + 6) % 11;
      const float d1a = (drok && coka) ? (w1a[i6] - mu1a) : 0.f;
      const float d1b = (drok && cokb) ? (w1b[i6] - mu1b) : 0.f;
      const float d2a = (drok && coka) ? (w2a[i6] - mu2a) : 0.f;
      const float d2b = (drok && cokb) ? (w2b[i6] - mu2b) : 0.f;

      // products computed locally in fp32, exchanged packed, blurred.
      // three sequential phases; centers stay fp32-exact.
      {
        const float qa = d1a * d1a, qb = d1b * d1b;
        const unsigned W = packh2(qa, qb);
        const unsigned l1 = xlane_u(W, a4 - 4), l2 = xlane_u(W, a4 - 8);
        const unsigned l3 = xlane_u(W, a4 - 12), r1 = xlane_u(W, a4 + 4);
        const unsigned r2 = xlane_u(W, a4 + 8), r3 = xlane_u(W, a4 + 12);
        float ha, hb;
        hblur12(g, l3, l2, l1, qa, qb, r1, r2, r3, ha, hb);
        p11w[c] = packh2(ha, hb);
      }
      {
        const float qa = d2a * d2a, qb = d2b * d2b;
        const unsigned W = packh2(qa, qb);
        const unsigned l1 = xlane_u(W, a4 - 4), l2 = xlane_u(W, a4 - 8);
        const unsigned l3 = xlane_u(W, a4 - 12), r1 = xlane_u(W, a4 + 4);
        const unsigned r2 = xlane_u(W, a4 + 8), r3 = xlane_u(W, a4 + 12);
        float ha, hb;
        hblur12(g, l3, l2, l1, qa, qb, r1, r2, r3, ha, hb);
        p22w[c] = packh2(ha, hb);
      }
      {
        const float qa = d1a * d2a, qb = d1b * d2b;
        const unsigned W = packh2(qa, qb);
        const unsigned l1 = xlane_u(W, a4 - 4), l2 = xlane_u(W, a4 - 8);
        const unsigned l3 = xlane_u(W, a4 - 12), r1 = xlane_u(W, a4 + 4);
        const unsigned r2 = xlane_u(W, a4 + 8), r3 = xlane_u(W, a4 + 12);
        float ha, hb;
        hblur12(g, l3, l2, l1, qa, qb, r1, r2, r3, ha, hb);
        p12w[c] = packh2(ha, hb);
      }

      // output row rt-10 (valid steps 20..83)
      if (t >= 20 && t < 84) {
        float s11a = 0.f, s11b = 0.f, s22a = 0.f, s22b = 0.f;
        float s12a = 0.f, s12b = 0.f;
        #pragma unroll
        for (int j = 0; j < 11; ++j) {
          const int ix = (c + 1 + j) % 11;
          const float gj = g[j];
          const unsigned u11 = p11w[ix], u22 = p22w[ix], u12 = p12w[ix];
          s11a = fmaf(gj, lo2f(u11), s11a);
          s11b = fmaf(gj, hi2f(u11), s11b);
          s22a = fmaf(gj, lo2f(u22), s22a);
          s22b = fmaf(gj, hi2f(u22), s22b);
          s12a = fmaf(gj, lo2f(u12), s12a);
          s12b = fmaf(gj, hi2f(u12), s12b);
        }
        const unsigned mw1 = m1w[i6], mw2 = m2w[i6];   // mu of row rt-10
        COMB(s11a, s22a, s12a, lo2f(mw1), lo2f(mw2), omaa);
        COMB(s11b, s22b, s12b, hi2f(mw1), hi2f(mw2), omab);
      }
    }
  }

  // wave reduction (64 lanes), then block partials via tiny LDS
  #pragma unroll
  for (int off = 32; off > 0; off >>= 1) {
    acc0 += __shfl_down(acc0, off);
    aC1 += __shfl_down(aC1, off);
    aC2 += __shfl_down(aC2, off);
    vmin = fminf(vmin, __shfl_down(vmin, off));
    vmax = fmaxf(vmax, __shfl_down(vmax, off));
  }
  if (lane == 0) {
    redbuf[wv][0] = acc0; redbuf[wv][1] = aC1; redbuf[wv][2] = aC2;
    redbuf[wv][3] = vmin; redbuf[wv][4] = vmax;
  }
  __syncthreads();
  if (tid == 0) {
    float t0 = 0.f, t1 = 0.f, t2 = 0.f, mn = 1e30f, mx = -1e30f;
    #pragma unroll
    for (int w2 = 0; w2 < 4; ++w2) {
      t0 += redbuf[w2][0]; t1 += redbuf[w2][1]; t2 += redbuf[w2][2];
      mn = fminf(mn, redbuf[w2][3]); mx = fmaxf(mx, redbuf[w2][4]);
    }
    float* wsF = (float*)ws;
    atomicAdd(&wsF[0], t0);
    atomicAdd(&wsF[1], t1);
    atomicAdd(&wsF[2], t2);
    atomicMin(&ws[3], fkey(mn));
    atomicMax(&ws[4], fkey(mx));

    // finalize in the last block (v6/v7-validated done-counter)
    __threadfence();
    unsigned done = atomicAdd(&ws[5], 1u);
    if (done == gridDim.x - 1) {
      float s0 = atomicAdd(&wsF[0], 0.f);      // device-scope atomic reads
      float sc1 = atomicAdd(&wsF[1], 0.f);
      float sc2 = atomicAdd(&wsF[2], 0.f);
      unsigned mnk = atomicMin(&ws[3], 0xFFFFFFFFu);
      unsigned mxk = atomicMax(&ws[4], 0u);
      float vr = funkey(mxk) - funkey(mnk) + 1e-5f;
      float c1 = 0.01f * vr; c1 *= c1;
      float c2 = 0.03f * vr; c2 *= c2;
      float mean = (s0 + c1 * sc1 + c2 * sc2) * (1.0f / 16777216.0f);
      out[0] = 1.f - mean;
    }
  }
}

extern "C" void kernel_launch(void* const* d_in, const int* in_sizes, int n_in,
                              void* d_out, int out_size, void* d_ws, size_t ws_size,
                              hipStream_t stream) {
  const float* img1 = (const float*)d_in[0];
  const float* img2 = (const float*)d_in[1];
  const float* kern = (const float*)d_in[2];
  unsigned* ws = (unsigned*)d_ws;
  float* out = (float*)d_out;
  (void)in_sizes; (void)n_in; (void)out_size; (void)ws_size;

  hipLaunchKernelGGL(ssim_init, dim3(1), dim3(1), 0, stream, ws);
  hipLaunchKernelGGL(ssim_main, dim3(NBLK), dim3(256), 0, stream,
                     img1, img2, kern, ws, out);
}

// Round 10
// 335.135 us; speedup vs baseline: 1.2304x; 1.2304x over previous
//
#include <hip/hip_runtime.h>
#include <hip/hip_fp16.h>

// SSIM, B=16, C=1, H=W=1024, 11x11 separable Gaussian.
// v9: v4 skeleton (6144 waves, 2 exchange phases/step, verified 230us) with
// packed-fp16 VALU math (v_pk_fma_f16) on the image-pair axis:
//   - mu: (mu1,mu2) accumulated as ONE half2 (2 hfma2/offset, was 4 mix-fma)
//   - hp: (d1^2,d2^2) packed squares (3 ops/offset, was 6); cross fp32 (mix)
//   - stats: p-window packed; (s11,s22) V-blur = 11 hfma2 (was 22 fma)
// Image V-blur, d, COMB stay fp32. ~-30% VALU ops/step; DS schedule untouched.
// K=2 verdict after v6 (spilled) and v8 (spill-free, still +39%): structurally
// worse -- 2560 waves = 2.4/SIMD can't hide bpermute latency. Abandoned.
// v7 lesson kept: g[] stays in VGPRs. Finalize merged (done-counter, validated).

#define IMG_H 1024
#define IMG_W 1024
#define USEC   44                      // useful cols per wave
#define NSTRIP 24                      // 24*44 = 1056 >= 1024
#define BAND   64                      // output rows per wave
#define NBAND  16
#define NBATCH 16
#define NWAVES (NSTRIP * NBAND * NBATCH)   // 6144
#define NBLK   (NWAVES / 4)                // 1536 blocks of 4 waves

__device__ __forceinline__ unsigned fkey(float f) {
  unsigned b = __float_as_uint(f);
  return (b & 0x80000000u) ? ~b : (b | 0x80000000u);
}
__device__ __forceinline__ float funkey(unsigned k) {
  return (k & 0x80000000u) ? __uint_as_float(k & 0x7FFFFFFFu)
                           : __uint_as_float(~k);
}
__device__ __forceinline__ unsigned xlane_u(unsigned v, int addr) {
  // full-wave (64-lane) register crossbar; addr in bytes, lane = addr[7:2]
  return (unsigned)__builtin_amdgcn_ds_bpermute(addr, (int)v);
}
__device__ __forceinline__ __half2 u2h(unsigned u) { return *(__half2*)&u; }
__device__ __forceinline__ unsigned h2u(__half2 h) { return *(unsigned*)&h; }

__global__ void ssim_init(unsigned* __restrict__ ws) {
  ws[0] = 0u;           // sum S0*B0
  ws[1] = 0u;           // sum S0*B'   (C1 coefficient)
  ws[2] = 0u;           // sum B0*S'   (C2 coefficient)
  ws[3] = 0xFFFFFFFFu;  // min key
  ws[4] = 0u;           // max key
  ws[5] = 0u;           // done-counter
}

__global__ __launch_bounds__(256, 2)
void ssim_main(const float* __restrict__ img1, const float* __restrict__ img2,
               const float* __restrict__ kern, unsigned* __restrict__ ws,
               float* __restrict__ out) {
  __shared__ float redbuf[4][8];

  const int tid = threadIdx.x;
  const int lane = tid & 63;
  const int wv = tid >> 6;
  const int wid = blockIdx.x * 4 + wv;

  const int strip = wid % NSTRIP;
  const int rem = wid / NSTRIP;
  const int band = rem % NBAND;
  const int batch = rem / NBAND;

  const size_t boff = (size_t)batch * (IMG_H * IMG_W);
  const float* i1 = img1 + boff;
  const float* i2 = img2 + boff;

  // separable weights: g[j] = k2d[5][j] / sqrt(k2d[5][5]) (VGPRs; v7 showed
  // SGPR-pinning starves ILP). gh[k] = half2(g[5+k]) for packed math
  // (symmetric: g[5-k] == g[5+k] bitwise).
  float g[11];
  #pragma unroll
  for (int j = 0; j < 11; ++j) g[j] = kern[55 + j] * rsqrtf(kern[60]);
  __half2 gh[6];
  #pragma unroll
  for (int k = 0; k < 6; ++k) gh[k] = __half2half2(__float2half_rn(g[5 + k]));

  const int col = strip * USEC + lane - 10;    // absolute column of this lane
  const bool cok = (col >= 0) && (col < IMG_W);
  const int cidx = min(max(col, 0), IMG_W - 1);
  const bool oma = (lane >= 10) && (lane < 54) && (col < IMG_W); // output lane
  const int r0 = band * BAND;
  const int a4 = lane * 4;                     // bpermute self byte-address

  // rolling windows (statically indexed -> registers)
  float w1[11] = {}, w2[11] = {};
  float m1w[11] = {}, m2w[11] = {};            // mu fp32 (COMB precision)
  unsigned psq[11] = {};                       // half2 (h11, h22)
  float p12[11] = {};                          // cross blur fp32

  float acc0 = 0.f, aC1 = 0.f, aC2 = 0.f;
  float vmin = 1e30f, vmax = -1e30f;

  // prefetch row for t = 0 (img row r0-10)
  float nv1, nv2;
  {
    int rin = r0 - 10;
    if ((unsigned)rin < IMG_H) {
      nv1 = i1[(size_t)rin * IMG_W + cidx];
      nv2 = i2[(size_t)rin * IMG_W + cidx];
    } else { nv1 = 0.f; nv2 = 0.f; }
  }

  #pragma unroll 1
  for (int m = 0; m < 8; ++m) {
    #pragma unroll
    for (int c = 0; c < 11; ++c) {
      const int t = m * 11 + c;                // step; img row rt = r0-10+t

      // commit prefetched row t (column-masked -> zero padding)
      float v1 = cok ? nv1 : 0.f;
      float v2 = cok ? nv2 : 0.f;
      w1[c] = v1; w2[c] = v2;
      vmin = fminf(vmin, fminf(v1, v2));       // pad zeros: negligible vs true min
      vmax = fmaxf(vmax, fmaxf(v1, v2));

      // prefetch row t+1 (latency hidden under this step's compute)
      if (t < 83) {
        int rin = r0 - 9 + t;
        if ((unsigned)rin < IMG_H) {
          nv1 = i1[(size_t)rin * IMG_W + cidx];
          nv2 = i2[(size_t)rin * IMG_W + cidx];
        } else { nv1 = 0.f; nv2 = 0.f; }
      } else { nv1 = 0.f; nv2 = 0.f; }

      // vertical blur over img rows rt-10..rt -> Vimg at row rt-5 (fp32)
      float V1 = 0.f, V2 = 0.f;
      #pragma unroll
      for (int j = 0; j < 11; ++j) {
        V1 = fmaf(g[j], w1[(c + 1 + j) % 11], V1);
        V2 = fmaf(g[j], w2[(c + 1 + j) % 11], V2);
      }

      // horizontal blur -> mu(rt-5), PACKED: (mu1,mu2) as one half2,
      // 2 hfma2 per offset. Exchange word = (V1,V2) packed half2.
      const unsigned pv = h2u(__floats2half2_rn(V1, V2));
      __half2 mu_pk = __hmul2(gh[0], u2h(pv));     // center
      #pragma unroll
      for (int o = 1; o <= 5; ++o) {
        const unsigned ul = xlane_u(pv, a4 - 4 * o);
        const unsigned ur = xlane_u(pv, a4 + 4 * o);
        mu_pk = __hfma2(gh[o], u2h(ul), mu_pk);
        mu_pk = __hfma2(gh[o], u2h(ur), mu_pk);
      }
      const float mu1 = __low2float(mu_pk);
      const float mu2 = __high2float(mu_pk);
      m1w[c] = mu1; m2w[c] = mu2;

      // d at row rt-5 (0 outside the image, matching zero-padded second conv)
      const bool drok = ((unsigned)(r0 - 15 + t) < IMG_H);
      const int i6 = (c + 6) % 11;
      const float d1 = (drok && cok) ? (w1[i6] - mu1) : 0.f;
      const float d2 = (drok && cok) ? (w2[i6] - mu2) : 0.f;

      // fused products + horizontal blur of (d1d1,d2d2) PACKED; cross fp32.
      const unsigned pd = h2u(__floats2half2_rn(d1, d2));
      const __half2 pdh = u2h(pd);
      __half2 acc_sq = __hmul2(gh[0], __hmul2(pdh, pdh));   // center squares
      float h12 = (g[5] * d1) * d2;                         // center cross
      #pragma unroll
      for (int o = 1; o <= 5; ++o) {
        const unsigned ulw = xlane_u(pd, a4 - 4 * o);
        const unsigned urw = xlane_u(pd, a4 + 4 * o);
        const __half2 ul = u2h(ulw), ur = u2h(urw);
        const __half2 ssum = __hfma2(ul, ul, __hmul2(ur, ur));  // (l1^2+r1^2, l2^2+r2^2)
        acc_sq = __hfma2(gh[o], ssum, acc_sq);
        const float cl = __low2float(ul) * __high2float(ul);    // mix-muls
        const float cr = __low2float(ur) * __high2float(ur);
        h12 = fmaf(g[5 + o], cl + cr, h12);
      }
      psq[c] = h2u(acc_sq);
      p12[c] = h12;

      // output row rt-10 (valid steps 20..83)
      if (t >= 20 && t < 84) {
        __half2 s_sq = u2h(0u);                 // (s11, s22) packed
        float s12 = 0.f;
        #pragma unroll
        for (int j = 0; j < 11; ++j) {
          const int ix = (c + 1 + j) % 11;
          const int k = (j < 5) ? (5 - j) : (j - 5);   // |j-5| (constant)
          s_sq = __hfma2(gh[k], u2h(psq[ix]), s_sq);
          s12 = fmaf(g[j], p12[ix], s12);
        }
        const float s11 = __low2float(s_sq);
        const float s22 = __high2float(s_sq);
        const float M1 = m1w[i6], M2 = m2w[i6];

        float s1 = s11 + 1.f;                  // sigma1_sq
        float s2 = s22 + 1.f;                  // sigma2_sq
        float sv = s12 + 1.f;                  // sigma12
        float a = 2.f * sv;
        float b = s1 + s2;                     // >= 2 on valid lanes
        float rb = __builtin_amdgcn_rcpf(b);
        float S0 = a * rb;
        float Sp = (b - a) * rb * rb;          // dS/dC2
        float m12 = fmaf(M1, M2, 1.f);
        float nb = 2.f * m12;
        float N1 = nb * nb;
        float ms = fmaf(M1, M1, fmaf(M2, M2, 2.f));
        float Dv = ms * ms;                    // >= 4 on valid lanes
        float rD = __builtin_amdgcn_rcpf(Dv);
        float B0 = N1 * rD;
        float Bp = (Dv - N1) * rD * rD;        // dB/dC1
        float t0v = S0 * B0, t1v = S0 * Bp, t2v = B0 * Sp;
        acc0 += oma ? t0v : 0.f;               // select blocks NaN from halo lanes
        aC1 += oma ? t1v : 0.f;
        aC2 += oma ? t2v : 0.f;
      }
    }
  }

  // wave reduction (64 lanes), then block partials via tiny LDS
  #pragma unroll
  for (int off = 32; off > 0; off >>= 1) {
    acc0 += __shfl_down(acc0, off);
    aC1 += __shfl_down(aC1, off);
    aC2 += __shfl_down(aC2, off);
    vmin = fminf(vmin, __shfl_down(vmin, off));
    vmax = fmaxf(vmax, __shfl_down(vmax, off));
  }
  if (lane == 0) {
    redbuf[wv][0] = acc0; redbuf[wv][1] = aC1; redbuf[wv][2] = aC2;
    redbuf[wv][3] = vmin; redbuf[wv][4] = vmax;
  }
  __syncthreads();
  if (tid == 0) {
    float t0 = 0.f, t1 = 0.f, t2 = 0.f, mn = 1e30f, mx = -1e30f;
    #pragma unroll
    for (int w2 = 0; w2 < 4; ++w2) {
      t0 += redbuf[w2][0]; t1 += redbuf[w2][1]; t2 += redbuf[w2][2];
      mn = fminf(mn, redbuf[w2][3]); mx = fmaxf(mx, redbuf[w2][4]);
    }
    float* wsF = (float*)ws;
    atomicAdd(&wsF[0], t0);
    atomicAdd(&wsF[1], t1);
    atomicAdd(&wsF[2], t2);
    atomicMin(&ws[3], fkey(mn));
    atomicMax(&ws[4], fkey(mx));

    // finalize in the last block (v6/v7-validated done-counter)
    __threadfence();                           // device-scope: order ws ops
    unsigned done = atomicAdd(&ws[5], 1u);
    if (done == gridDim.x - 1) {
      float s0 = atomicAdd(&wsF[0], 0.f);      // device-scope atomic reads
      float sc1 = atomicAdd(&wsF[1], 0.f);
      float sc2 = atomicAdd(&wsF[2], 0.f);
      unsigned mnk = atomicMin(&ws[3], 0xFFFFFFFFu);
      unsigned mxk = atomicMax(&ws[4], 0u);
      float vr = funkey(mxk) - funkey(mnk) + 1e-5f;
      float c1 = 0.01f * vr; c1 *= c1;
      float c2 = 0.03f * vr; c2 *= c2;
      float mean = (s0 + c1 * sc1 + c2 * sc2) * (1.0f / 16777216.0f);
      out[0] = 1.f - mean;
    }
  }
}

extern "C" void kernel_launch(void* const* d_in, const int* in_sizes, int n_in,
                              void* d_out, int out_size, void* d_ws, size_t ws_size,
                              hipStream_t stream) {
  const float* img1 = (const float*)d_in[0];
  const float* img2 = (const float*)d_in[1];
  const float* kern = (const float*)d_in[2];
  unsigned* ws = (unsigned*)d_ws;
  float* out = (float*)d_out;
  (void)in_sizes; (void)n_in; (void)out_size; (void)ws_size;

  hipLaunchKernelGGL(ssim_init, dim3(1), dim3(1), 0, stream, ws);
  hipLaunchKernelGGL(ssim_main, dim3(NBLK), dim3(256), 0, stream,
                     img1, img2, kern, ws, out);
}